// Round 1
// 312.481 us; speedup vs baseline: 1.0660x; 1.0660x over previous
//
#include <hip/hip_runtime.h>

// MultiHeadSelfAttention: BS=4, S=2048, DIM=768, H=12, DH=64
// R3: fused QKV proj launch (1152 blocks, XCD-swizzled, X-panel-sharing order),
//     fused converts, attn K/V register double-buffer prefetch (loads issued one
//     KV-tile ahead), sadd dropped from LDS (mask recomputed on az path only).
// MFMA layouts (learn_hip m89/m91): A/B-frag: [m|n = lane&15][k = quad*8+j]
//                                   C/D: col = lane&15, row = quad*4 + reg

#define BSZ 4
#define SEQ 2048
#define DIMD 768
#define NHD 12
#define MTOT (BSZ*SEQ)      // 8192
#define WELEM (DIMD*DIMD)   // 589824

typedef __bf16 bf16;
typedef __attribute__((ext_vector_type(8))) __bf16 bf16x8;
typedef __attribute__((ext_vector_type(4))) __bf16 bf16x4;
typedef __attribute__((ext_vector_type(4))) float f32x4;

__device__ __forceinline__ f32x4 mfma_bf16(bf16x8 a, bf16x8 b, f32x4 c) {
    return __builtin_amdgcn_mfma_f32_16x16x32_bf16(a, b, c, 0, 0, 0);
}

__device__ __forceinline__ void async16(const bf16* g, bf16* l) {
    __builtin_amdgcn_global_load_lds(
        (const __attribute__((address_space(1))) unsigned int*)g,
        (__attribute__((address_space(3))) unsigned int*)l, 16, 0, 0);
}

// ---------------- converts ----------------
__global__ __launch_bounds__(256) void convert_w_kernel(
    const float* __restrict__ w0, const float* __restrict__ w1,
    const float* __restrict__ w2, const float* __restrict__ w3,
    bf16* __restrict__ out) {
    const int z = blockIdx.y;
    const float* src = (z == 0) ? w0 : (z == 1) ? w1 : (z == 2) ? w2 : w3;
    const int i = (blockIdx.x * 256 + threadIdx.x) * 4;
    float4 v = *(const float4*)(src + i);
    bf16x4 o;
    o[0] = (bf16)v.x; o[1] = (bf16)v.y; o[2] = (bf16)v.z; o[3] = (bf16)v.w;
    *(bf16x4*)(out + (size_t)z * WELEM + i) = o;
}

__global__ __launch_bounds__(256) void convert_x_kernel(
    const float* __restrict__ x0, const float* __restrict__ x1,
    const float* __restrict__ x2,
    bf16* __restrict__ d0, bf16* __restrict__ d1, bf16* __restrict__ d2) {
    const int z = blockIdx.y;
    const float* src = (z == 0) ? x0 : (z == 1) ? x1 : x2;
    bf16* dst = (z == 0) ? d0 : (z == 1) ? d1 : d2;
    const int i = (blockIdx.x * 256 + threadIdx.x) * 4;
    float4 v = *(const float4*)(src + i);
    bf16x4 o;
    o[0] = (bf16)v.x; o[1] = (bf16)v.y; o[2] = (bf16)v.z; o[3] = (bf16)v.w;
    *(bf16x4*)(dst + i) = o;
}

// ---------------- shared 128x128xK768 GEMM core ----------------
// D[m][n] = sum_k A[m][k]*B[n][k], A/B row-major K-contiguous, K=768.
// LDS tiles 128x64 bf16, unpadded rows (128B) with XOR-8 column-block swizzle.
__device__ __forceinline__ void gemm_core_768(
    const bf16* __restrict__ Ag, const bf16* __restrict__ Bg,
    int m0, int n0, bf16* As, bf16* Bs, f32x4 (&acc)[4][4]) {
    const int tid = threadIdx.x;
    const int lane = tid & 63, wv = tid >> 6;
    const int quad = lane >> 4, l16 = lane & 15;
    const int wr = wv >> 1, wc = wv & 1;
    const int rr = lane >> 3, cbl = lane & 7;
    const int swz = l16 & 7;
    for (int kt = 0; kt < 12; ++kt) {
        if (kt) __syncthreads();                  // prior frag reads done
        for (int c = 0; c < 4; ++c) {
            const int row = c * 32 + wv * 8 + rr;
            const int cb = cbl ^ (row & 7);       // swizzled source col-block
            const size_t gcol = (size_t)kt * 64 + cb * 8;
            async16(Ag + (size_t)(m0 + row) * 768 + gcol, As + row * 64 + cbl * 8);
            async16(Bg + (size_t)(n0 + row) * 768 + gcol, Bs + row * 64 + cbl * 8);
        }
        __syncthreads();                          // drains vmcnt, LDS visible
        for (int ks = 0; ks < 2; ++ks) {
            bf16x8 af[4], bfr[4];
            for (int t = 0; t < 4; ++t)
                af[t] = *(const bf16x8*)(As + (wr * 64 + t * 16 + l16) * 64 +
                                         (((ks * 4 + quad) ^ swz) * 8));
            for (int t = 0; t < 4; ++t)
                bfr[t] = *(const bf16x8*)(Bs + (wc * 64 + t * 16 + l16) * 64 +
                                          (((ks * 4 + quad) ^ swz) * 8));
            for (int ti = 0; ti < 4; ++ti)
                for (int tj = 0; tj < 4; ++tj)
                    acc[ti][tj] = mfma_bf16(af[ti], bfr[tj], acc[ti][tj]);
        }
    }
}

// ---------------- fused QKV projection ----------------
// One launch, 1152 blocks. Work id (XCD-swizzled): z in {Q,K,V}, rt = row tile (64),
// xt = feature tile (6). xt fastest so the 6 blocks sharing an X row-panel are
// consecutive and land on one XCD (L2 panel reuse).
// z<2 (Q,K): swapped operands (A=W m=feat, B=X n=rows) -> out [b][h][s][dh]
// z=2 (V):   A=X (m=rows), B=W (n=feat)                -> out [b][h][dh][s]
__global__ __launch_bounds__(256, 3) void proj_kernel(
    const bf16* __restrict__ Xq, const bf16* __restrict__ Xk, const bf16* __restrict__ Xv,
    const bf16* __restrict__ W,
    const float* __restrict__ bq, const float* __restrict__ bk, const float* __restrict__ bv,
    bf16* __restrict__ Qo, bf16* __restrict__ Ko, bf16* __restrict__ Vo) {
    __shared__ __align__(16) bf16 smem[2 * 128 * 64];
    bf16* As = smem;
    bf16* Bs = smem + 128 * 64;
    const int lin = blockIdx.x;
    const int swzb = (lin & 7) * 144 + (lin >> 3);      // bijective: 1152 % 8 == 0
    const int z = swzb / 384;
    const int rem = swzb - z * 384;
    const int rt = rem / 6;                             // row tile (0..63)
    const int xt = rem - rt * 6;                        // feature tile (0..5)
    const bf16* X = (z == 0) ? Xq : (z == 1) ? Xk : Xv;
    const bf16* Wz = W + (size_t)z * WELEM;
    const float* bias = (z == 0) ? bq : (z == 1) ? bk : bv;
    bf16* Out = (z == 0) ? Qo : (z == 1) ? Ko : Vo;

    const int tid = threadIdx.x;
    const int lane = tid & 63, wv = tid >> 6;
    const int quad = lane >> 4, l16 = lane & 15;
    const int wr = wv >> 1, wc = wv & 1;
    f32x4 acc[4][4] = {};
    int m0, n0;
    const bf16 *Ag, *Bg;
    if (z < 2) { m0 = xt * 128; n0 = rt * 128; Ag = Wz; Bg = X; }
    else       { m0 = rt * 128; n0 = xt * 128; Ag = X;  Bg = Wz; }
    gemm_core_768(Ag, Bg, m0, n0, As, Bs, acc);
    __syncthreads();                              // As/Bs reads done; reuse as Ot
    bf16* Ot = smem;                              // 128x128 bf16 tile
    if (z < 2) {
        const float scale = (z == 0) ? 0.125f : 1.0f;
        for (int ti = 0; ti < 4; ++ti) {
            const int featl = wr * 64 + ti * 16 + quad * 4;
            const float4 b4 = *(const float4*)(bias + m0 + featl);
            for (int tj = 0; tj < 4; ++tj) {
                const int sl = wc * 64 + tj * 16 + l16;
                bf16x4 pk;
                pk[0] = (bf16)((acc[ti][tj][0] + b4.x) * scale);
                pk[1] = (bf16)((acc[ti][tj][1] + b4.y) * scale);
                pk[2] = (bf16)((acc[ti][tj][2] + b4.z) * scale);
                pk[3] = (bf16)((acc[ti][tj][3] + b4.w) * scale);
                *(bf16x4*)&Ot[sl * 128 + featl] = pk;   // Ot[s][feat]
            }
        }
        __syncthreads();
        for (int it = 0; it < 8; ++it) {
            const int unit = it * 256 + tid;      // 16B units of the tile
            const int s = unit >> 4, u = unit & 15;
            const int feat = m0 + u * 8;
            const int hh = feat >> 6, dh = feat & 63;
            const int srow = n0 + s;
            const int bb = srow >> 11, s2 = srow & 2047;
            *(bf16x8*)&Out[((size_t)(bb * NHD + hh) * SEQ + s2) * 64 + dh] =
                *(const bf16x8*)&Ot[s * 128 + u * 8];
        }
    } else {
        for (int ti = 0; ti < 4; ++ti) {
            const int sl = wr * 64 + ti * 16 + quad * 4;
            for (int tj = 0; tj < 4; ++tj) {
                const int featl = wc * 64 + tj * 16 + l16;
                const float bv = bias[n0 + featl];
                bf16x4 pk;
                pk[0] = (bf16)(acc[ti][tj][0] + bv);
                pk[1] = (bf16)(acc[ti][tj][1] + bv);
                pk[2] = (bf16)(acc[ti][tj][2] + bv);
                pk[3] = (bf16)(acc[ti][tj][3] + bv);
                *(bf16x4*)&Ot[featl * 128 + sl] = pk;   // Ot[feat][s]
            }
        }
        __syncthreads();
        const int bb = m0 >> 11, sbase = m0 & 2047;
        for (int it = 0; it < 8; ++it) {
            const int unit = it * 256 + tid;
            const int fl = unit >> 4, u = unit & 15;
            const int feat = n0 + fl;
            const int hh = feat >> 6, dh = feat & 63;
            *(bf16x8*)&Out[((size_t)(bb * NHD + hh) * 64 + dh) * SEQ + sbase + u * 8] =
                *(const bf16x8*)&Ot[fl * 128 + u * 8];
        }
    }
}

// ---------------- flash attention ----------------
// grid (SEQ/128=16, 12, 4), block 256. Q-tile 128 (each wave owns 32 queries, 2 strips).
// Phase 1: S^T = K.Q^T with K frags from REGISTER double-buffer (prefetched one KV
// tile ahead, issued right after current tile's QK MFMAs); online softmax; P -> LDS
// (dbuf). Phase 2: O^T += V^T.P^T with prefetched V^T frags. 1 barrier per KV tile.
__global__ __launch_bounds__(256, 3) void attn_kernel(
    const bf16* __restrict__ Qb, const bf16* __restrict__ Kb, const bf16* __restrict__ Vb,
    const int* __restrict__ mask, bf16* __restrict__ CTX) {
    __shared__ __align__(16) bf16 Ps[2][128][72];
    __shared__ float alphas[2][128];
    __shared__ float invs[128];
    __shared__ int anyz_s;
    const int tid = threadIdx.x;
    const int lane = tid & 63, wv = tid >> 6, quad = lane >> 4, l16 = lane & 15;
    const int b = blockIdx.z, h = blockIdx.y, qt = blockIdx.x;
    const int bh = b * NHD + h;
    if (tid == 0) anyz_s = 0;
    __syncthreads();
    {
        int4 m0v = *(const int4*)(mask + b * SEQ + tid * 8);
        int4 m1v = *(const int4*)(mask + b * SEQ + tid * 8 + 4);
        if (!(m0v.x && m0v.y && m0v.z && m0v.w && m1v.x && m1v.y && m1v.z && m1v.w))
            anyz_s = 1;
    }
    // loop-invariant Q fragments (B operand), 2 strips of 16 queries
    bf16x8 qf0[2], qf1[2];
    for (int st = 0; st < 2; ++st) {
        const bf16* qp = Qb + ((size_t)bh * SEQ + qt * 128 + wv * 32 + st * 16 + l16) * 64;
        qf0[st] = *(const bf16x8*)(qp + quad * 8);
        qf1[st] = *(const bf16x8*)(qp + 32 + quad * 8);
    }
    const bf16* Kp = Kb + (size_t)bh * SEQ * 64 + (size_t)l16 * 64 + quad * 8;
    const bf16* Vp = Vb + (size_t)bh * 64 * SEQ + (size_t)(wv * 16 + l16) * SEQ + quad * 8;
    const int* Mp = mask + b * SEQ;
    f32x4 acc_o[8] = {};
    float rm[2] = {-1e30f, -1e30f}, rs[2] = {0.f, 0.f};
    __syncthreads();
    const int az = anyz_s;

    // K/V fragment double buffers (static names; 2x unrolled loop — no runtime idx)
    bf16x8 kfa0[4], kfa1[4], vfa0, vfa1;
    bf16x8 kfb0[4], kfb1[4], vfb0, vfb1;
    for (int jj = 0; jj < 4; ++jj) {               // prologue: tile 0 -> A set
        const bf16* kp = Kp + (size_t)(jj * 16) * 64;
        kfa0[jj] = *(const bf16x8*)kp;
        kfa1[jj] = *(const bf16x8*)(kp + 32);
    }
    vfa0 = *(const bf16x8*)Vp;
    vfa1 = *(const bf16x8*)(Vp + 32);

#define ATT_STEP(KT, KC0, KC1, VC0, VC1, KN0, KN1, VN0, VN1) do {                  \
        const int kt_ = (KT);                                                      \
        const int buf_ = kt_ & 1;                                                  \
        const int k0_ = kt_ * 64;                                                  \
        f32x4 sc[2][4];                                                            \
        for (int st = 0; st < 2; ++st)                                             \
            for (int jj = 0; jj < 4; ++jj) {                                       \
                f32x4 zf = {};                                                     \
                zf = mfma_bf16(KC0[jj], qf0[st], zf);                              \
                sc[st][jj] = mfma_bf16(KC1[jj], qf1[st], zf);                      \
            }                                                                      \
        {   /* prefetch next tile (clamped on last iter; extra loads harmless) */  \
            const int kn_ = (kt_ + 1 < SEQ / 64) ? (kt_ + 1) * 64 : kt_ * 64;      \
            for (int jj = 0; jj < 4; ++jj) {                                       \
                const bf16* kp_ = Kp + (size_t)(kn_ + jj * 16) * 64;               \
                KN0[jj] = *(const bf16x8*)kp_;                                     \
                KN1[jj] = *(const bf16x8*)(kp_ + 32);                              \
            }                                                                      \
            VN0 = *(const bf16x8*)(Vp + kn_);                                      \
            VN1 = *(const bf16x8*)(Vp + kn_ + 32);                                 \
        }                                                                          \
        if (az)                                                                    \
            for (int jj = 0; jj < 4; ++jj) {                                       \
                const int4 mm = *(const int4*)(Mp + k0_ + jj * 16 + quad * 4);     \
                float4 sa;                                                         \
                sa.x = mm.x ? 0.f : -1e30f; sa.y = mm.y ? 0.f : -1e30f;            \
                sa.z = mm.z ? 0.f : -1e30f; sa.w = mm.w ? 0.f : -1e30f;            \
                for (int st = 0; st < 2; ++st) {                                   \
                    sc[st][jj][0] += sa.x; sc[st][jj][1] += sa.y;                  \
                    sc[st][jj][2] += sa.z; sc[st][jj][3] += sa.w;                  \
                }                                                                  \
            }                                                                      \
        for (int st = 0; st < 2; ++st) {                                           \
            float tmax = -1e30f;                                                   \
            for (int jj = 0; jj < 4; ++jj)                                         \
                for (int r = 0; r < 4; ++r) tmax = fmaxf(tmax, sc[st][jj][r]);     \
            tmax = fmaxf(tmax, __shfl_xor(tmax, 16));                              \
            tmax = fmaxf(tmax, __shfl_xor(tmax, 32));                              \
            const float nmax = fmaxf(rm[st], tmax);                                \
            const float alpha = __expf(rm[st] - nmax);                             \
            rm[st] = nmax;                                                         \
            float tsum = 0.f;                                                      \
            for (int jj = 0; jj < 4; ++jj) {                                       \
                bf16x4 pk;                                                         \
                for (int r = 0; r < 4; ++r) {                                      \
                    const float p = __expf(sc[st][jj][r] - nmax);                  \
                    tsum += p;                                                     \
                    pk[r] = (bf16)p;                                               \
                }                                                                  \
                *(bf16x4*)&Ps[buf_][wv * 32 + st * 16 + l16][jj * 16 + quad * 4] = pk; \
            }                                                                      \
            tsum += __shfl_xor(tsum, 16);                                          \
            tsum += __shfl_xor(tsum, 32);                                          \
            rs[st] = rs[st] * alpha + tsum;                                        \
            if (lane < 16) alphas[buf_][wv * 32 + st * 16 + lane] = alpha;         \
        }                                                                          \
        __syncthreads();                         /* Ps/alphas[buf_] visible */     \
        for (int qj = 0; qj < 8; ++qj) {                                           \
            const float al = alphas[buf_][qj * 16 + l16];                          \
            f32x4 c = acc_o[qj];                                                   \
            c[0] *= al; c[1] *= al; c[2] *= al; c[3] *= al;                        \
            bf16x8 pf0 = *(const bf16x8*)&Ps[buf_][qj * 16 + l16][quad * 8];       \
            bf16x8 pf1 = *(const bf16x8*)&Ps[buf_][qj * 16 + l16][32 + quad * 8];  \
            c = mfma_bf16(VC0, pf0, c);                                            \
            c = mfma_bf16(VC1, pf1, c);                                            \
            acc_o[qj] = c;                                                         \
        }                                                                          \
    } while (0)

    for (int kt2 = 0; kt2 < SEQ / 128; ++kt2) {
        ATT_STEP(kt2 * 2,     kfa0, kfa1, vfa0, vfa1, kfb0, kfb1, vfb0, vfb1);
        ATT_STEP(kt2 * 2 + 1, kfb0, kfb1, vfb0, vfb1, kfa0, kfa1, vfa0, vfa1);
    }
#undef ATT_STEP

    if (lane < 16) {
        invs[wv * 32 + lane] = 1.0f / rs[0];
        invs[wv * 32 + 16 + lane] = 1.0f / rs[1];
    }
    __syncthreads();
    for (int qj = 0; qj < 8; ++qj) {
        const float inv = invs[qj * 16 + l16];
        bf16x4 pk;
        for (int r = 0; r < 4; ++r) pk[r] = (bf16)(acc_o[qj][r] * inv);
        const int s = qt * 128 + qj * 16 + l16;
        *(bf16x4*)&CTX[(size_t)(b * SEQ + s) * DIMD + h * 64 + wv * 16 + quad * 4] = pk;
    }
}

// ---------------- output projection (XCD-swizzled, ctx-panel-sharing order) ----------------
__global__ __launch_bounds__(256, 3) void oproj_kernel(
    const bf16* __restrict__ ctx, const bf16* __restrict__ wo,
    const float* __restrict__ bo, float* __restrict__ out) {
    __shared__ __align__(16) bf16 smem[2 * 128 * 64];
    const int lin = blockIdx.x;
    const int swzb = (lin & 7) * 48 + (lin >> 3);       // bijective: 384 % 8 == 0
    const int rt = swzb / 6;                            // ctx row tile (0..63)
    const int xt = swzb - rt * 6;                       // feature tile (0..5)
    const int tid = threadIdx.x;
    const int lane = tid & 63, wv = tid >> 6;
    const int quad = lane >> 4, l16 = lane & 15;
    const int wr = wv >> 1, wc = wv & 1;
    const int m0 = rt * 128, n0 = xt * 128;
    f32x4 acc[4][4] = {};
    gemm_core_768(ctx, wo, m0, n0, smem, smem + 128 * 64, acc);
    for (int ti = 0; ti < 4; ++ti) {
        const int rowb = m0 + wr * 64 + ti * 16 + quad * 4;
        for (int tj = 0; tj < 4; ++tj) {
            const int feat = n0 + wc * 64 + tj * 16 + l16;
            const float bv = bo[feat];
            for (int r = 0; r < 4; ++r)
                out[(size_t)(rowb + r) * DIMD + feat] = acc[ti][tj][r] + bv;
        }
    }
}

extern "C" void kernel_launch(void* const* d_in, const int* in_sizes, int n_in,
                              void* d_out, int out_size, void* d_ws, size_t ws_size,
                              hipStream_t stream) {
    const float* query = (const float*)d_in[0];
    const float* key_t = (const float*)d_in[1];
    const float* value = (const float*)d_in[2];
    const int*   mask  = (const int*)d_in[3];
    const float* q_w = (const float*)d_in[4];
    const float* q_b = (const float*)d_in[5];
    const float* k_w = (const float*)d_in[6];
    const float* k_b = (const float*)d_in[7];
    const float* v_w = (const float*)d_in[8];
    const float* v_b = (const float*)d_in[9];
    const float* o_w = (const float*)d_in[10];
    const float* o_b = (const float*)d_in[11];
    float* out = (float*)d_out;

    bf16* ws  = (bf16*)d_ws;
    bf16* W   = ws;                                  // 4 x WELEM
    bf16* XBq = ws + (size_t)4 * WELEM;              // bf16 inputs (all 3 live for fused proj)
    bf16* XBk = XBq + (size_t)MTOT * DIMD;
    bf16* XBv = XBk + (size_t)MTOT * DIMD;
    bf16* Qb  = XBv + (size_t)MTOT * DIMD;           // [b][h][s][dh]
    bf16* Kb  = Qb + (size_t)MTOT * DIMD;            // [b][h][s][dh]
    bf16* Vb  = Kb + (size_t)MTOT * DIMD;            // [b][h][dh][s]
    bf16* CTX = XBq;                                 // alias: XBq dead after proj

    convert_w_kernel<<<dim3(WELEM / 1024, 4), 256, 0, stream>>>(q_w, k_w, v_w, o_w, W);
    convert_x_kernel<<<dim3(MTOT * DIMD / 1024, 3), 256, 0, stream>>>(
        query, key_t, value, XBq, XBk, XBv);

    proj_kernel<<<1152, 256, 0, stream>>>(XBq, XBk, XBv, W, q_b, k_b, v_b, Qb, Kb, Vb);

    attn_kernel<<<dim3(SEQ / 128, NHD, BSZ), 256, 0, stream>>>(Qb, Kb, Vb, mask, CTX);
    oproj_kernel<<<384, 256, 0, stream>>>(CTX, W + (size_t)3 * WELEM, o_b, out);
}